// Round 14
// baseline (6564.754 us; speedup 1.0000x reference)
//
#include <hip/hip_runtime.h>
#include <hip/hip_bf16.h>
#include <math.h>

typedef __attribute__((ext_vector_type(8))) short bf16x8;
typedef __attribute__((ext_vector_type(4))) float f32x4;

static constexpr int Tc = 512, HIDc = 512;
static constexpr int NWGc = 256, THR = 256;

// ws byte offsets. Slabs are bf16 [64 batch][512 k] = 64 KB each.
static constexpr size_t WSB_H0  = 0;                     // [3] h0(t) at t%3
static constexpr size_t WSB_H1  = WSB_H0 + 3ull * 65536; // [2] h1(t) at t&1
static constexpr size_t WSB_Z   = WSB_H1 + 2ull * 65536; // 2 KB zero emb row (fp32)
static constexpr size_t WSB_CTR = WSB_Z + 2048;          // 32 arrival lines, 64B apart
static constexpr size_t WSB_EPO = WSB_CTR + 2048;        // epoch flag, own line
static constexpr size_t WSB_FLG = WSB_EPO + 64;          // 256 init flags, 64B apart
static constexpr size_t WSB_END = WSB_FLG + 256 * 64;

static constexpr unsigned FMAGIC = 0x1357acedu;  // init-done flag value
static constexpr unsigned EPBASE = 0x40000000u;  // epoch base (post-init)
static constexpr int SPIN_CAP = 1 << 15;         // worst-case total ~10s, never 600s

__device__ __forceinline__ unsigned ld_devu(const unsigned* p) {
    return __hip_atomic_load(p, __ATOMIC_RELAXED, __HIP_MEMORY_SCOPE_AGENT);
}
__device__ __forceinline__ unsigned long long ld_devu64(const unsigned long long* p) {
    return __hip_atomic_load(p, __ATOMIC_RELAXED, __HIP_MEMORY_SCOPE_AGENT);
}
__device__ __forceinline__ void st_devu(unsigned* p, unsigned v) {
    __hip_atomic_store(p, v, __ATOMIC_RELAXED, __HIP_MEMORY_SCOPE_AGENT);
}
template<int N> __device__ __forceinline__ void s_wait_vm() {
    asm volatile("s_waitcnt vmcnt(%0)" :: "n"(N) : "memory");
}
__device__ __forceinline__ void s_wait_lgkm() {
    asm volatile("s_waitcnt lgkmcnt(0)" ::: "memory");
}
__device__ __forceinline__ void wgbar() {
    asm volatile("" ::: "memory");
    __builtin_amdgcn_s_barrier();
    asm volatile("" ::: "memory");
}
__device__ __forceinline__ unsigned short bfc(float f) {
    __hip_bfloat16 h = __float2bfloat16(f);
    return *(unsigned short*)&h;
}
__device__ __forceinline__ float bf2f(unsigned short u) {
    __hip_bfloat16 h; *(unsigned short*)&h = u;
    return __bfloat162float(h);
}

// 16 cache-bypassing 16B loads of one slab row-slice (self-contained:
// internal vmcnt(0); early-clobber outputs). Load i covers frag (c=i>>2, s=i&3).
__device__ __forceinline__ void ld_slab16(const char* slab, unsigned voff,
                                          bf16x8* f) {
    asm volatile(
        "global_load_dwordx4 %0, %16, %17 sc0 sc1\n\t"
        "global_load_dwordx4 %1, %16, %17 offset:64 sc0 sc1\n\t"
        "global_load_dwordx4 %2, %16, %17 offset:128 sc0 sc1\n\t"
        "global_load_dwordx4 %3, %16, %17 offset:192 sc0 sc1\n\t"
        "global_load_dwordx4 %4, %16, %17 offset:256 sc0 sc1\n\t"
        "global_load_dwordx4 %5, %16, %17 offset:320 sc0 sc1\n\t"
        "global_load_dwordx4 %6, %16, %17 offset:384 sc0 sc1\n\t"
        "global_load_dwordx4 %7, %16, %17 offset:448 sc0 sc1\n\t"
        "global_load_dwordx4 %8, %16, %17 offset:512 sc0 sc1\n\t"
        "global_load_dwordx4 %9, %16, %17 offset:576 sc0 sc1\n\t"
        "global_load_dwordx4 %10, %16, %17 offset:640 sc0 sc1\n\t"
        "global_load_dwordx4 %11, %16, %17 offset:704 sc0 sc1\n\t"
        "global_load_dwordx4 %12, %16, %17 offset:768 sc0 sc1\n\t"
        "global_load_dwordx4 %13, %16, %17 offset:832 sc0 sc1\n\t"
        "global_load_dwordx4 %14, %16, %17 offset:896 sc0 sc1\n\t"
        "global_load_dwordx4 %15, %16, %17 offset:960 sc0 sc1\n\t"
        "s_waitcnt vmcnt(0)"
        : "=&v"(f[0]), "=&v"(f[1]), "=&v"(f[2]), "=&v"(f[3]),
          "=&v"(f[4]), "=&v"(f[5]), "=&v"(f[6]), "=&v"(f[7]),
          "=&v"(f[8]), "=&v"(f[9]), "=&v"(f[10]), "=&v"(f[11]),
          "=&v"(f[12]), "=&v"(f[13]), "=&v"(f[14]), "=&v"(f[15])
        : "v"(voff), "s"(slab)
        : "memory");
}

__global__ __launch_bounds__(THR, 1)
void lstm_persistent(const int* __restrict__ xp,
                     const float* __restrict__ emb,
                     const float* __restrict__ W0,
                     const float* __restrict__ b0,
                     const float* __restrict__ W1,
                     const float* __restrict__ b1,
                     const float* __restrict__ fcw,
                     const float* __restrict__ fcb,
                     float* __restrict__ out,
                     float* __restrict__ ws)
{
    char* wsc = (char*)ws;

    unsigned* ctr = (unsigned*)(wsc + WSB_CTR);
    unsigned* epo = (unsigned*)(wsc + WSB_EPO);
    unsigned* flg = (unsigned*)(wsc + WSB_FLG);
    const float* zrow = (const float*)(wsc + WSB_Z);

    __shared__ float preF[16 * 68];   // gate preacts [w-row][batch], pad 68
    __shared__ float hexF[4 * 64];    // h exchange [h_local][batch]

    const int  tid   = threadIdx.x;
    const int  wg    = blockIdx.x;
    const bool lead  = (wg == 0);     // resident leader (also computes, post-publish)
    const bool is_l0 = (wg < 128);
    const int  hw    = (is_l0 ? wg : wg - 128) * 4;
    const float* Wb  = is_l0 ? W0 : W1;
    const float* bb  = is_l0 ? b0 : b1;
    const int  b_    = tid & 63;
    const int  wv    = __builtin_amdgcn_readfirstlane(tid >> 6);
    // MFMA lane decomposition (16x16x32): n = lane&15, q = lane>>4
    const int  n = tid & 15;
    const int  q = (tid & 63) >> 4;
    const int  b_row = wv * 16 + n;                          // lane's batch row
    const unsigned rowB = (unsigned)(b_row * 1024 + q * 16); // byte off in slab

    // ---- diagnostic sentinel: proves launch (overwritten by real FC) ----
    if (wg == 0 && tid < 64) out[tid] = 0.25f;

    // ---- init: zero the 5 h slabs + the 2KB zero emb row ----
    {
        unsigned long long* hz = (unsigned long long*)(wsc + WSB_H0);
        for (int i = wg * THR + tid; i < 5 * 8192 + 256; i += NWGc * THR)
            __hip_atomic_store(hz + i, 0ull, __ATOMIC_RELAXED, __HIP_MEMORY_SCOPE_AGENT);
    }

    // ---- B-fragments: wave's 16 weight rows (w-row n), bf16, in VGPRs ----
    // frag f covers k in [f*32, f*32+32); lane holds k = f*32 + q*8 .. +8
    bf16x8 bw[32];
    {
        const float* wrow = Wb + (size_t)((n >> 2) * HIDc + hw + (n & 3)) * 1024;
        #pragma unroll
        for (int f = 0; f < 32; ++f) {
            const int k0 = f * 32 + q * 8;
            const float4 u0 = *(const float4*)(wrow + k0);
            const float4 u1 = *(const float4*)(wrow + k0 + 4);
            union { unsigned short us[8]; bf16x8 v; } pk;
            pk.us[0] = bfc(u0.x); pk.us[1] = bfc(u0.y);
            pk.us[2] = bfc(u0.z); pk.us[3] = bfc(u0.w);
            pk.us[4] = bfc(u1.x); pk.us[5] = bfc(u1.y);
            pk.us[6] = bfc(u1.z); pk.us[7] = bfc(u1.w);
            bw[f] = pk.v;
        }
    }
    const float bias_n = bb[(n >> 2) * HIDc + hw + (n & 3)];

    // ---- init barrier (poison-tolerant; wg0 zeroes counters, publishes) ----
    s_wait_vm<0>();
    wgbar();
    if (tid == 0) st_devu(&flg[wg * 16], FMAGIC);
    if (wg == 0) {
        if (tid == 0) {
            for (int g = 0; g < NWGc; ++g) {
                int gu = 0;
                while (ld_devu(&flg[g * 16]) != FMAGIC && ++gu < SPIN_CAP)
                    __builtin_amdgcn_s_sleep(1);
            }
        }
        wgbar();
        for (int i = tid; i < 512; i += THR) st_devu(&ctr[i], 0u);  // 32 lines
        s_wait_vm<0>();
        wgbar();
        if (tid == 0) st_devu(epo, EPBASE);
    } else if (tid == 0) {
        int gu = 0;
        while (ld_devu(epo) != EPBASE && ++gu < SPIN_CAP)
            __builtin_amdgcn_s_sleep(1);
    }
    wgbar();

    float cpriv = 0.0f;
    f32x4 acc;

    // A-half for step w (loads + 16 MFMAs into acc)
    auto A_half = [&](int w) {
        if (is_l0) {
            // direct emb-table gather (immutable inputs -> cached loads)
            const int tok = xp[b_row * Tc + w];
            const float* er = tok ? (emb + (size_t)tok * 512) : zrow;
            #pragma unroll
            for (int c = 0; c < 4; ++c) {
                #pragma unroll
                for (int s = 0; s < 4; ++s) {
                    const int k0 = c * 128 + s * 32 + q * 8;
                    const float4 lo = *(const float4*)(er + k0);
                    const float4 hi = *(const float4*)(er + k0 + 4);
                    union { unsigned short us[8]; bf16x8 v; } pk;
                    pk.us[0] = bfc(lo.x); pk.us[1] = bfc(lo.y);
                    pk.us[2] = bfc(lo.z); pk.us[3] = bfc(lo.w);
                    pk.us[4] = bfc(hi.x); pk.us[5] = bfc(hi.y);
                    pk.us[6] = bfc(hi.z); pk.us[7] = bfc(hi.w);
                    acc = __builtin_amdgcn_mfma_f32_16x16x32_bf16(
                        pk.v, bw[c * 4 + s], acc, 0, 0, 0);
                }
            }
        } else {
            // h0(w-2): guaranteed complete by gate w-1 (previous iteration)
            bf16x8 fa[16];
            ld_slab16(wsc + WSB_H0 + (size_t)((w - 2) % 3) * 65536, rowB, fa);
            #pragma unroll
            for (int i = 0; i < 16; ++i)
                acc = __builtin_amdgcn_mfma_f32_16x16x32_bf16(fa[i], bw[i], acc, 0, 0, 0);
        }
    };

    #pragma unroll 1
    for (int w = 0; w <= Tc + 1; ++w) {
        const bool a0  = is_l0 && (w < Tc);     // layer0 computes t=w
        const bool a1  = !is_l0 && (w >= 2);    // layer1 computes t=w-2
        const bool act = a0 || a1;

        acc = f32x4{0.f, 0.f, 0.f, 0.f};

        if (lead) {
            // ---- PUBLISH-FIRST: poll arrivals(w) -> publish epoch w ----
            if (tid == 0) {
                const unsigned tgt = (unsigned)NWGc * (unsigned)w;
                int gu = 0;
                for (;;) {
                    unsigned s = 0;
                    #pragma unroll
                    for (int g = 0; g < 32; ++g) s += ld_devu(&ctr[g * 16]);
                    if (s >= tgt || ++gu >= SPIN_CAP) break;
                }
                st_devu(epo, EPBASE + 1u + (unsigned)w);
            }
            wgbar();
            // leader's own A-half AFTER the publish (emb path: dependency-free)
            if (act) A_half(w);
        } else {
            // ---- pre-spin A-half (overlaps the gate wait) ----
            if (act) A_half(w);
            if (tid == 0) {
                int gu = 0;
                while (ld_devu(epo) < EPBASE + 1u + (unsigned)w && ++gu < SPIN_CAP)
                    __builtin_amdgcn_s_sleep(1);
            }
            wgbar();
        }

        if (act) {
            // ---- B-half: recurrent slab, 16B sc0/sc1 loads + 16 MFMAs ----
            const char* slabB = is_l0
                ? (wsc + WSB_H0 + (size_t)((w + 2) % 3) * 65536)      // h0(w-1)
                : (wsc + WSB_H1 + (size_t)((w - 3) & 1) * 65536);     // h1(w-3)
            bf16x8 fb[16];
            ld_slab16(slabB, rowB, fb);
            #pragma unroll
            for (int i = 0; i < 16; ++i)
                acc = __builtin_amdgcn_mfma_f32_16x16x32_bf16(fb[i], bw[16 + i], acc, 0, 0, 0);

            // ---- gate exchange: lane reg r holds D[batch q*4+r][w-row n] ----
            *(f32x4*)(preF + (size_t)n * 68 + wv * 16 + q * 4) = acc + bias_n;
            s_wait_lgkm(); wgbar();

            // cell update: thread (b_, h_local = wv); gate g at w-row g*4+wv
            const float pI = preF[(0 * 4 + wv) * 68 + b_];
            const float pF = preF[(1 * 4 + wv) * 68 + b_];
            const float pO = preF[(2 * 4 + wv) * 68 + b_];
            const float pG = preF[(3 * 4 + wv) * 68 + b_];
            const float ig = 1.f / (1.f + expf(-pI));
            const float fg = 1.f / (1.f + expf(-pF));
            const float og = 1.f / (1.f + expf(-pO));
            const float gg = fmaxf(pG, 0.f);
            cpriv = fg * cpriv + ig * gg;
            const float hn = og * fmaxf(cpriv, 0.f);
            hexF[wv * 64 + b_] = hn;
            s_wait_lgkm(); wgbar();

            // h-write: wave 0 packs 4 bf16 -> one 8 B store per batch row
            if (tid < 64) {
                unsigned long long pk = 0;
                #pragma unroll
                for (int jj = 0; jj < 4; ++jj)
                    pk |= (unsigned long long)bfc(hexF[jj * 64 + tid]) << (16 * jj);
                unsigned short* hdst = is_l0
                    ? (unsigned short*)(wsc + WSB_H0 + (size_t)(w % 3) * 65536)
                    : (unsigned short*)(wsc + WSB_H1 + (size_t)((w - 2) & 1) * 65536);
                __hip_atomic_store((unsigned long long*)(hdst + (size_t)tid * 512 + hw),
                                   pk, __ATOMIC_RELAXED, __HIP_MEMORY_SCOPE_AGENT);
            }
        }

        // ---- arrive for barrier w+1 (32-way striped) ----
        s_wait_vm<0>();   // h-store acked at coherent point
        wgbar();
        if (tid == 0)
            __hip_atomic_fetch_add(&ctr[(wg & 31) * 16], 1u, __ATOMIC_RELAXED,
                                   __HIP_MEMORY_SCOPE_AGENT);
    }

    // ---- clear own init flag (replay-race hardening) ----
    if (tid == 0) st_devu(&flg[wg * 16], 0u);

    // ---- final FC + sigmoid on h1(Tc-1) ----
    if (wg == 0) {
        if (tid == 0) {
            const unsigned tgt = (unsigned)NWGc * (unsigned)(Tc + 2);
            int gu = 0;
            for (;;) {
                unsigned s = 0;
                #pragma unroll
                for (int g = 0; g < 32; ++g) s += ld_devu(&ctr[g * 16]);
                if (s >= tgt || ++gu >= SPIN_CAP) break;
            }
        }
        wgbar();
        if (tid < 64) {
            const unsigned short* h1f =
                (const unsigned short*)(wsc + WSB_H1 + (size_t)((Tc - 1) & 1) * 65536)
                + (size_t)tid * 512;
            float s = fcb[0];
            for (int h = 0; h < HIDc; h += 4) {
                const unsigned long long u = ld_devu64((const unsigned long long*)(h1f + h));
                s = fmaf(bf2f((unsigned short)(u        & 0xffff)), fcw[h + 0], s);
                s = fmaf(bf2f((unsigned short)((u >> 16) & 0xffff)), fcw[h + 1], s);
                s = fmaf(bf2f((unsigned short)((u >> 32) & 0xffff)), fcw[h + 2], s);
                s = fmaf(bf2f((unsigned short)((u >> 48) & 0xffff)), fcw[h + 3], s);
            }
            out[tid] = 1.f / (1.f + expf(-s));
        }
    }
}

extern "C" void kernel_launch(void* const* d_in, const int* in_sizes, int n_in,
                              void* d_out, int out_size, void* d_ws, size_t ws_size,
                              hipStream_t stream) {
    const int*   xp  = (const int*)d_in[0];
    const float* emb = (const float*)d_in[1];
    const float* W0  = (const float*)d_in[2];
    const float* b0  = (const float*)d_in[3];
    const float* W1  = (const float*)d_in[4];
    const float* b1  = (const float*)d_in[5];
    const float* fcw = (const float*)d_in[6];
    const float* fcb = (const float*)d_in[7];
    float* out = (float*)d_out;
    float* ws  = (float*)d_ws;

    if (ws_size < WSB_END) return;  // loud fail: out stays poisoned

    // Plain launch: 256 WGs x 256 thr, 1 WG/CU on 256 CUs -> co-resident.
    lstm_persistent<<<dim3(NWGc), dim3(THR), 0, stream>>>(
        xp, emb, W0, b0, W1, b1, fcw, fcb, out, ws);
}

// Round 15
// 5949.656 us; speedup vs baseline: 1.1034x; 1.1034x over previous
//
#include <hip/hip_runtime.h>
#include <hip/hip_bf16.h>
#include <math.h>

typedef __attribute__((ext_vector_type(8))) short bf16x8;
typedef __attribute__((ext_vector_type(4))) float f32x4;

static constexpr int Tc = 512, HIDc = 512;
static constexpr int NWGc = 128, THR = 256;   // 64 WGs per layer, 32 w-rows each

// ws byte offsets. Slabs are bf16 [64 batch][512 k] = 64 KB each.
static constexpr size_t WSB_H0  = 0;                     // [3] h0(t) at t%3
static constexpr size_t WSB_H1  = WSB_H0 + 3ull * 65536; // [2] h1(t) at t&1
static constexpr size_t WSB_Z   = WSB_H1 + 2ull * 65536; // 2 KB zero emb row (fp32)
static constexpr size_t WSB_CTR = WSB_Z + 2048;          // 8 arrival lines, 64B apart
static constexpr size_t WSB_EPO = WSB_CTR + 2048;        // epoch flag, own line
static constexpr size_t WSB_FLG = WSB_EPO + 64;          // 128 init flags, 64B apart
static constexpr size_t WSB_END = WSB_FLG + 256 * 64;

static constexpr unsigned FMAGIC = 0x1357acedu;  // init-done flag value
static constexpr unsigned EPBASE = 0x40000000u;  // epoch base (post-init)
static constexpr int SPIN_CAP = 1 << 15;         // fail fast, never a 600s hang

__device__ __forceinline__ unsigned ld_devu(const unsigned* p) {
    return __hip_atomic_load(p, __ATOMIC_RELAXED, __HIP_MEMORY_SCOPE_AGENT);
}
__device__ __forceinline__ unsigned long long ld_devu64(const unsigned long long* p) {
    return __hip_atomic_load(p, __ATOMIC_RELAXED, __HIP_MEMORY_SCOPE_AGENT);
}
__device__ __forceinline__ void st_devu(unsigned* p, unsigned v) {
    __hip_atomic_store(p, v, __ATOMIC_RELAXED, __HIP_MEMORY_SCOPE_AGENT);
}
template<int N> __device__ __forceinline__ void s_wait_vm() {
    asm volatile("s_waitcnt vmcnt(%0)" :: "n"(N) : "memory");
}
__device__ __forceinline__ void s_wait_lgkm() {
    asm volatile("s_waitcnt lgkmcnt(0)" ::: "memory");
}
__device__ __forceinline__ void wgbar() {
    asm volatile("" ::: "memory");
    __builtin_amdgcn_s_barrier();
    asm volatile("" ::: "memory");
}
__device__ __forceinline__ unsigned short bfc(float f) {
    __hip_bfloat16 h = __float2bfloat16(f);
    return *(unsigned short*)&h;
}
__device__ __forceinline__ float bf2f(unsigned short u) {
    __hip_bfloat16 h; *(unsigned short*)&h = u;
    return __bfloat162float(h);
}

// 16 cache-bypassing 16B loads of one slab row-slice (self-contained:
// internal vmcnt(0); early-clobber outputs). Load i covers frag (c=i>>2, s=i&3).
__device__ __forceinline__ void ld_slab16(const char* slab, unsigned voff,
                                          bf16x8* f) {
    asm volatile(
        "global_load_dwordx4 %0, %16, %17 sc0 sc1\n\t"
        "global_load_dwordx4 %1, %16, %17 offset:64 sc0 sc1\n\t"
        "global_load_dwordx4 %2, %16, %17 offset:128 sc0 sc1\n\t"
        "global_load_dwordx4 %3, %16, %17 offset:192 sc0 sc1\n\t"
        "global_load_dwordx4 %4, %16, %17 offset:256 sc0 sc1\n\t"
        "global_load_dwordx4 %5, %16, %17 offset:320 sc0 sc1\n\t"
        "global_load_dwordx4 %6, %16, %17 offset:384 sc0 sc1\n\t"
        "global_load_dwordx4 %7, %16, %17 offset:448 sc0 sc1\n\t"
        "global_load_dwordx4 %8, %16, %17 offset:512 sc0 sc1\n\t"
        "global_load_dwordx4 %9, %16, %17 offset:576 sc0 sc1\n\t"
        "global_load_dwordx4 %10, %16, %17 offset:640 sc0 sc1\n\t"
        "global_load_dwordx4 %11, %16, %17 offset:704 sc0 sc1\n\t"
        "global_load_dwordx4 %12, %16, %17 offset:768 sc0 sc1\n\t"
        "global_load_dwordx4 %13, %16, %17 offset:832 sc0 sc1\n\t"
        "global_load_dwordx4 %14, %16, %17 offset:896 sc0 sc1\n\t"
        "global_load_dwordx4 %15, %16, %17 offset:960 sc0 sc1\n\t"
        "s_waitcnt vmcnt(0)"
        : "=&v"(f[0]), "=&v"(f[1]), "=&v"(f[2]), "=&v"(f[3]),
          "=&v"(f[4]), "=&v"(f[5]), "=&v"(f[6]), "=&v"(f[7]),
          "=&v"(f[8]), "=&v"(f[9]), "=&v"(f[10]), "=&v"(f[11]),
          "=&v"(f[12]), "=&v"(f[13]), "=&v"(f[14]), "=&v"(f[15])
        : "v"(voff), "s"(slab)
        : "memory");
}

__global__ __launch_bounds__(THR, 1)
void lstm_persistent(const int* __restrict__ xp,
                     const float* __restrict__ emb,
                     const float* __restrict__ W0,
                     const float* __restrict__ b0,
                     const float* __restrict__ W1,
                     const float* __restrict__ b1,
                     const float* __restrict__ fcw,
                     const float* __restrict__ fcb,
                     float* __restrict__ out,
                     float* __restrict__ ws)
{
    char* wsc = (char*)ws;

    unsigned* ctr = (unsigned*)(wsc + WSB_CTR);
    unsigned* epo = (unsigned*)(wsc + WSB_EPO);
    unsigned* flg = (unsigned*)(wsc + WSB_FLG);
    const float* zrow = (const float*)(wsc + WSB_Z);

    __shared__ float preF[32 * 68];   // gate preacts [w-row 0..31][batch]
    __shared__ float hexF[8 * 64];    // h exchange [h_local 0..7][batch]

    const int  tid   = threadIdx.x;
    const int  wg    = blockIdx.x;
    const bool is_l0 = (wg < 64);
    const int  hw    = (is_l0 ? wg : wg - 64) * 8;   // 8 h-outputs per WG
    const float* Wb  = is_l0 ? W0 : W1;
    const float* bb  = is_l0 ? b0 : b1;
    const int  b_    = tid & 63;
    const int  wv    = __builtin_amdgcn_readfirstlane(tid >> 6);
    // MFMA lane decomposition (16x16x32): n = lane&15, q = lane>>4
    const int  n = tid & 15;
    const int  q = (tid & 63) >> 4;
    const int  b_row = wv * 16 + n;                          // lane's batch row
    const unsigned rowB = (unsigned)(b_row * 1024 + q * 16); // byte off in slab

    // ---- diagnostic sentinel: proves launch (overwritten by real FC) ----
    if (wg == 0 && tid < 64) out[tid] = 0.25f;

    // ---- init: zero the 5 h slabs + the 2KB zero emb row ----
    {
        unsigned long long* hz = (unsigned long long*)(wsc + WSB_H0);
        for (int i = wg * THR + tid; i < 5 * 8192 + 256; i += NWGc * THR)
            __hip_atomic_store(hz + i, 0ull, __ATOMIC_RELAXED, __HIP_MEMORY_SCOPE_AGENT);
    }

    // ---- B-fragments: wave's 32 weight rows (2 sets of 16), bf16, VGPRs ----
    // set s covers h columns hw + s*4 + (n&3), gate n>>2.
    // bw[h*32 + s*16 + f]: half h (A=0/B=1), set s, k-frag f
    //   -> k0 = h*512 + f*32 + q*8
    bf16x8 bw[64];
    float bias_s[2];
    {
        #pragma unroll
        for (int s = 0; s < 2; ++s) {
            const float* wrow =
                Wb + (size_t)((n >> 2) * HIDc + hw + s * 4 + (n & 3)) * 1024;
            #pragma unroll
            for (int f = 0; f < 32; ++f) {   // f<16: A-half, f>=16: B-half
                const int k0 = f * 32 + q * 8;
                const float4 u0 = *(const float4*)(wrow + k0);
                const float4 u1 = *(const float4*)(wrow + k0 + 4);
                union { unsigned short us[8]; bf16x8 v; } pk;
                pk.us[0] = bfc(u0.x); pk.us[1] = bfc(u0.y);
                pk.us[2] = bfc(u0.z); pk.us[3] = bfc(u0.w);
                pk.us[4] = bfc(u1.x); pk.us[5] = bfc(u1.y);
                pk.us[6] = bfc(u1.z); pk.us[7] = bfc(u1.w);
                bw[(f >> 4) * 32 + s * 16 + (f & 15)] = pk.v;
            }
            bias_s[s] = bb[(n >> 2) * HIDc + hw + s * 4 + (n & 3)];
        }
    }

    // ---- init barrier (poison-tolerant; wg0 zeroes counters, publishes) ----
    s_wait_vm<0>();
    wgbar();
    if (tid == 0) st_devu(&flg[wg * 16], FMAGIC);
    if (wg == 0) {
        if (tid == 0) {
            for (int g = 0; g < NWGc; ++g) {
                int gu = 0;
                while (ld_devu(&flg[g * 16]) != FMAGIC && ++gu < SPIN_CAP)
                    __builtin_amdgcn_s_sleep(1);
            }
        }
        wgbar();
        for (int i = tid; i < 512; i += THR) st_devu(&ctr[i], 0u);
        s_wait_vm<0>();
        wgbar();
        if (tid == 0) st_devu(epo, EPBASE);
    } else if (tid == 0) {
        int gu = 0;
        while (ld_devu(epo) != EPBASE && ++gu < SPIN_CAP)
            __builtin_amdgcn_s_sleep(1);
    }
    wgbar();

    float cpriv0 = 0.0f, cpriv1 = 0.0f;   // c for h_local = wv and wv+4
    f32x4 acc0, acc1;

    // A-half for step w: load 16 A-frags once, MFMA against both B-sets
    auto A_half = [&](int w) {
        if (is_l0) {
            const int tok = xp[b_row * Tc + w];
            const float* er = tok ? (emb + (size_t)tok * 512) : zrow;
            #pragma unroll
            for (int f = 0; f < 16; ++f) {
                const int k0 = f * 32 + q * 8;
                const float4 lo = *(const float4*)(er + k0);
                const float4 hi = *(const float4*)(er + k0 + 4);
                union { unsigned short us[8]; bf16x8 v; } pk;
                pk.us[0] = bfc(lo.x); pk.us[1] = bfc(lo.y);
                pk.us[2] = bfc(lo.z); pk.us[3] = bfc(lo.w);
                pk.us[4] = bfc(hi.x); pk.us[5] = bfc(hi.y);
                pk.us[6] = bfc(hi.z); pk.us[7] = bfc(hi.w);
                acc0 = __builtin_amdgcn_mfma_f32_16x16x32_bf16(pk.v, bw[f], acc0, 0, 0, 0);
                acc1 = __builtin_amdgcn_mfma_f32_16x16x32_bf16(pk.v, bw[16 + f], acc1, 0, 0, 0);
            }
        } else {
            bf16x8 fa[16];
            ld_slab16(wsc + WSB_H0 + (size_t)((w - 2) % 3) * 65536, rowB, fa);
            #pragma unroll
            for (int f = 0; f < 16; ++f) {
                acc0 = __builtin_amdgcn_mfma_f32_16x16x32_bf16(fa[f], bw[f], acc0, 0, 0, 0);
                acc1 = __builtin_amdgcn_mfma_f32_16x16x32_bf16(fa[f], bw[16 + f], acc1, 0, 0, 0);
            }
        }
    };

    #pragma unroll 1
    for (int w = 0; w <= Tc + 1; ++w) {
        const bool a0  = is_l0 && (w < Tc);     // layer0 computes t=w
        const bool a1  = !is_l0 && (w >= 2);    // layer1 computes t=w-2
        const bool act = a0 || a1;

        acc0 = f32x4{0.f, 0.f, 0.f, 0.f};
        acc1 = f32x4{0.f, 0.f, 0.f, 0.f};

        // ---- pre-spin A-half (round-12 order: leader computes FIRST) ----
        if (act) A_half(w);

        // ---- leader/epoch barrier w ----
        if (wg == 0) {
            if (tid == 0) {
                const unsigned tgt = (unsigned)NWGc * (unsigned)w;
                int gu = 0;
                for (;;) {
                    unsigned s = 0;
                    #pragma unroll
                    for (int g = 0; g < 8; ++g) s += ld_devu(&ctr[g * 16]);
                    if (s >= tgt || ++gu >= SPIN_CAP) break;
                }
                st_devu(epo, EPBASE + 1u + (unsigned)w);
            }
        } else {
            if (tid == 0) {
                int gu = 0;
                while (ld_devu(epo) < EPBASE + 1u + (unsigned)w && ++gu < SPIN_CAP)
                    __builtin_amdgcn_s_sleep(1);
            }
        }
        wgbar();

        if (act) {
            // ---- B-half: recurrent slab loaded once, both B-sets ----
            const char* slabB = is_l0
                ? (wsc + WSB_H0 + (size_t)((w + 2) % 3) * 65536)      // h0(w-1)
                : (wsc + WSB_H1 + (size_t)((w - 3) & 1) * 65536);     // h1(w-3)
            bf16x8 fb[16];
            ld_slab16(slabB, rowB, fb);
            #pragma unroll
            for (int f = 0; f < 16; ++f) {
                acc0 = __builtin_amdgcn_mfma_f32_16x16x32_bf16(fb[f], bw[32 + f], acc0, 0, 0, 0);
                acc1 = __builtin_amdgcn_mfma_f32_16x16x32_bf16(fb[f], bw[48 + f], acc1, 0, 0, 0);
            }

            // ---- gate exchange: row rr = set*16+n, col b = q*4+reg ----
            *(f32x4*)(preF + (size_t)n * 68 + wv * 16 + q * 4) = acc0 + bias_s[0];
            *(f32x4*)(preF + (size_t)(16 + n) * 68 + wv * 16 + q * 4) = acc1 + bias_s[1];
            s_wait_lgkm(); wgbar();

            // cell update: thread (b_, h_locals wv and wv+4)
            // row for (gate g, h_local hl) = (hl>>2)*16 + g*4 + (hl&3)
            #pragma unroll
            for (int half = 0; half < 2; ++half) {
                const int hl = wv + half * 4;
                const int rbase = (hl >> 2) * 16 + (hl & 3);
                const float pI = preF[(rbase + 0 * 4) * 68 + b_];
                const float pF = preF[(rbase + 1 * 4) * 68 + b_];
                const float pO = preF[(rbase + 2 * 4) * 68 + b_];
                const float pG = preF[(rbase + 3 * 4) * 68 + b_];
                const float ig = 1.f / (1.f + expf(-pI));
                const float fg = 1.f / (1.f + expf(-pF));
                const float og = 1.f / (1.f + expf(-pO));
                const float gg = fmaxf(pG, 0.f);
                float& cp = half ? cpriv1 : cpriv0;
                cp = fg * cp + ig * gg;
                hexF[hl * 64 + b_] = og * fmaxf(cp, 0.f);
            }
            s_wait_lgkm(); wgbar();

            // h-write: wave 0 packs 8 bf16 -> two 8 B stores per batch row
            if (tid < 64) {
                unsigned long long pk0 = 0, pk1 = 0;
                #pragma unroll
                for (int jj = 0; jj < 4; ++jj) {
                    pk0 |= (unsigned long long)bfc(hexF[jj * 64 + tid]) << (16 * jj);
                    pk1 |= (unsigned long long)bfc(hexF[(4 + jj) * 64 + tid]) << (16 * jj);
                }
                unsigned short* hdst = is_l0
                    ? (unsigned short*)(wsc + WSB_H0 + (size_t)(w % 3) * 65536)
                    : (unsigned short*)(wsc + WSB_H1 + (size_t)((w - 2) & 1) * 65536);
                __hip_atomic_store((unsigned long long*)(hdst + (size_t)tid * 512 + hw),
                                   pk0, __ATOMIC_RELAXED, __HIP_MEMORY_SCOPE_AGENT);
                __hip_atomic_store((unsigned long long*)(hdst + (size_t)tid * 512 + hw + 4),
                                   pk1, __ATOMIC_RELAXED, __HIP_MEMORY_SCOPE_AGENT);
            }
        }

        // ---- arrive for barrier w+1 ----
        s_wait_vm<0>();   // h-stores acked at coherent point
        wgbar();
        if (tid == 0)
            __hip_atomic_fetch_add(&ctr[(wg & 7) * 16], 1u, __ATOMIC_RELAXED,
                                   __HIP_MEMORY_SCOPE_AGENT);
    }

    // ---- clear own init flag (replay-race hardening) ----
    if (tid == 0) st_devu(&flg[wg * 16], 0u);

    // ---- final FC + sigmoid on h1(Tc-1) ----
    if (wg == 0) {
        if (tid == 0) {
            const unsigned tgt = (unsigned)NWGc * (unsigned)(Tc + 2);
            int gu = 0;
            for (;;) {
                unsigned s = 0;
                #pragma unroll
                for (int g = 0; g < 8; ++g) s += ld_devu(&ctr[g * 16]);
                if (s >= tgt || ++gu >= SPIN_CAP) break;
            }
        }
        wgbar();
        if (tid < 64) {
            const unsigned short* h1f =
                (const unsigned short*)(wsc + WSB_H1 + (size_t)((Tc - 1) & 1) * 65536)
                + (size_t)tid * 512;
            float s = fcb[0];
            for (int h = 0; h < HIDc; h += 4) {
                const unsigned long long u = ld_devu64((const unsigned long long*)(h1f + h));
                s = fmaf(bf2f((unsigned short)(u        & 0xffff)), fcw[h + 0], s);
                s = fmaf(bf2f((unsigned short)((u >> 16) & 0xffff)), fcw[h + 1], s);
                s = fmaf(bf2f((unsigned short)((u >> 32) & 0xffff)), fcw[h + 2], s);
                s = fmaf(bf2f((unsigned short)((u >> 48) & 0xffff)), fcw[h + 3], s);
            }
            out[tid] = 1.f / (1.f + expf(-s));
        }
    }
}

extern "C" void kernel_launch(void* const* d_in, const int* in_sizes, int n_in,
                              void* d_out, int out_size, void* d_ws, size_t ws_size,
                              hipStream_t stream) {
    const int*   xp  = (const int*)d_in[0];
    const float* emb = (const float*)d_in[1];
    const float* W0  = (const float*)d_in[2];
    const float* b0  = (const float*)d_in[3];
    const float* W1  = (const float*)d_in[4];
    const float* b1  = (const float*)d_in[5];
    const float* fcw = (const float*)d_in[6];
    const float* fcb = (const float*)d_in[7];
    float* out = (float*)d_out;
    float* ws  = (float*)d_ws;

    if (ws_size < WSB_END) return;  // loud fail: out stays poisoned

    // 128 WGs x 256 thr, 1 WG/CU -> trivially co-resident.
    lstm_persistent<<<dim3(NWGc), dim3(THR), 0, stream>>>(
        xp, emb, W0, b0, W1, b1, fcw, fcb, out, ws);
}